// Round 5
// baseline (1050.161 us; speedup 1.0000x reference)
//
#include <hip/hip_runtime.h>
#include <hip/hip_bf16.h>

// Decoder_12249246728712 — fused fp16-MFMA, TD=64, 2 WG/CU, latency-optimized spans.
//  r5 = r4 (never benched: GPU acquisition timeout) + stride-bug fix in chunk4:
//   * convGemm: wave-static (ot,rt) ownership -> B-frags loaded ONCE per stage (hoisted).
//   * dual accumulators -> half-length dependent MFMA chains.
//   * S1 RMW eliminated: s = conv([true;pred], W_aug) with identity block (k=2,c=32+o).
//   * S5(chunk4) + S6(te0) merged into one barrier span; chunk8/projAcc frags hoisted
//     out of the j-loop; next tile's enc inputs prefetched during S7.
//   * chunk4 now takes per-input strides (out0 lives in Bb @ S56, lt1 in A @ S40).
//   * LDS 81,856 B -> 2 WG/CU.

typedef _Float16 h16;
typedef _Float16 h16x8 __attribute__((ext_vector_type(8)));
typedef _Float16 h16x4 __attribute__((ext_vector_type(4)));
typedef float    f32x4 __attribute__((ext_vector_type(4)));

#define MFMA16(a,b,c) __builtin_amdgcn_mfma_f32_16x16x32_f16((a),(b),(c),0,0,0)

__device__ __forceinline__ int clampi(int x, int lo, int hi){ return x < lo ? lo : (x > hi ? hi : x); }
__device__ __forceinline__ float eluf(float v){ return v > 0.f ? v : (__expf(v) - 1.f); }

// LDS row strides (h16 elements) — 16B multiples, non-pow2.
#define S40  40
#define S56  56
#define S72  72
#define S104 104
#define SO2  72     // OUT2T [32][64 used]

#define ROWS 80     // 8 halo + 64 + 8 halo
#define RT5  5      // row-tiles of 16

// packed-weight element offsets in d_ws (h16 elements)
enum {
  OFF_WAUG = 0,      // [32][5][64]  (wz1 augmented with identity for pred)
  OFF_WOUT = 10240,  // [32][5][32]
  OFF_WTE1 = 15360,  // [32][5][32]
  OFF_WCM1 = 20480,  // [32][5][64]
  OFF_WTE0 = 30720,  // [48][5][64]
  OFF_WCM0 = 46080,  // [48][5][96]
  OFF_WM0  = 69120,  // [16][32]  q=koff*4+c (q<20)
  OFF_WM20 = 69632,  // [16][32]
  OFF_WM1  = 70144,  // [32][64]  q=koff*8+c (q<40)
  OFF_WM21 = 72192,  // [32][64]
  OFF_WP   = 74240,  // [48][512] rows jj*5+k (<35)
  PACKED_TOTAL = 98816
};

// ---------------- weight packing ----------------
__global__ void pack_weights(const float* wz1, const float* wout, const float* wte1,
    const float* wcm1, const float* wte0, const float* wcm0,
    const float* wm0, const float* wm20, const float* wm1, const float* wm21,
    const float* wproj, h16* wp)
{
  const int t = threadIdx.x;
  auto packBig = [&](const float* src, int O, int C, h16* dst, int Opad, int Cpad){
    const int n = Opad*5*Cpad;
    for (int i = t; i < n; i += blockDim.x){
      int c = i % Cpad; int k = (i / Cpad) % 5; int o = i / (Cpad*5);
      float v = (o < O && c < C) ? src[(o*C + c)*5 + k] : 0.f;
      dst[i] = (h16)v;
    }
  };
  switch (blockIdx.x){
    case 0: { // WAUG [32][5][64]: c<32 -> wz1; c==32+o,k==2 -> 1 (identity for pred)
      for (int i = t; i < 32*5*64; i += blockDim.x){
        int c = i & 63; int k = (i >> 6) % 5; int o = i / 320;
        float v = 0.f;
        if (o < 24){
          if (c < 32) v = wz1[(o*32 + c)*5 + k];
          else if (c == 32 + o && k == 2) v = 1.f;
        }
        wp[OFF_WAUG + i] = (h16)v;
      }
    } break;
    case 1: packBig(wout, 24, 24, wp+OFF_WOUT, 32, 32); break;
    case 2: packBig(wte1, 24, 32, wp+OFF_WTE1, 32, 32); break;
    case 3: packBig(wcm1, 24, 48, wp+OFF_WCM1, 32, 64); break;
    case 4: packBig(wte0, 48, 64, wp+OFF_WTE0, 48, 64); break;
    case 5: packBig(wcm0, 48, 96, wp+OFF_WCM0, 48, 96); break;
    case 6: {
      for (int i = t; i < 512; i += blockDim.x){
        int q = i & 31, o = i >> 5; float v = 0.f;
        if (o < 8 && q < 20){ int k = q >> 2, c = q & 3; v = wm0[(o*4 + c)*5 + k]; }
        wp[OFF_WM0 + i] = (h16)v;
      }
      for (int i = t; i < 512; i += blockDim.x){
        int q = i & 31, o = i >> 5; float v = 0.f;
        if (o < 8 && q < 20){ int k = q >> 2, c = q & 3; v = wm20[(o*4 + c)*5 + k]; }
        wp[OFF_WM20 + i] = (h16)v;
      }
    } break;
    case 7: {
      for (int i = t; i < 2048; i += blockDim.x){
        int q = i & 63, o = i >> 6; float v = 0.f;
        if (o < 24 && q < 40){ int k = q >> 3, c = q & 7; v = wm1[(o*8 + c)*5 + k]; }
        wp[OFF_WM1 + i] = (h16)v;
      }
      for (int i = t; i < 2048; i += blockDim.x){
        int q = i & 63, o = i >> 6; float v = 0.f;
        if (o < 24 && q < 40){ int k = q >> 3, c = q & 7; v = wm21[(o*8 + c)*5 + k]; }
        wp[OFF_WM21 + i] = (h16)v;
      }
    } break;
    case 8: {
      for (int i = t; i < 48*512; i += blockDim.x){
        int d = i & 511, r = i >> 9; float v = 0.f;
        if (r < 35){ int jj = r / 5, k = r - jj*5; v = wproj[(jj*512 + d)*5 + k]; }
        wp[OFF_WP + i] = (h16)v;
      }
    } break;
  }
}

// ---------------- device helpers ----------------

// Global [C][512] fp32 -> LDS XT[row=d][col=c] h16 (transposed), zero outside range.
__device__ __forceinline__ void loadT(const float* __restrict__ src, int C, int CB16,
    h16* __restrict__ XT, int S, int co, int d0, int wave, int lane)
{
  const int m = lane & 15, q = lane >> 4;
  const int UNITS = CB16*RT5;
  for (int u = wave; u < UNITS; u += 8){
    const int cb = u / RT5, db = u - cb*RT5;
    const int row = db*16 + m;
    const int dg = d0 - 8 + row;
    const bool dok = ((unsigned)dg < 512u);
    const int cbase = cb*16 + q*4;
    h16x4 pk;
    #pragma unroll
    for (int i = 0; i < 4; ++i){
      const int c = cbase + i;
      float v = (dok && c < C) ? src[c*512 + dg] : 0.f;
      pk[i] = (h16)v;
    }
    *(h16x4*)(XT + row*S + co + cbase) = pk;
  }
}

__device__ __forceinline__ void zeroCols(h16* XT, int S, int c0, int nc, int tid){
  for (int i = tid; i < ROWS*nc; i += 512){
    const int r = i / nc, c = i - r*nc;
    XT[r*S + c0 + c] = (h16)0.f;
  }
}

// Conv-GEMM, wave-static (ot,rt) ownership: B-frags loaded once per call.
// EPI 1: elu(acc) store; EPI 2: plain store. Rows with global d outside [0,512) -> 0.
template<int CB, int OT, int EPI>
__device__ __forceinline__ void convGemm(const h16* __restrict__ XT, int S,
    const h16* __restrict__ Wp, h16* __restrict__ XTo, int So, int co,
    int Oreal, int d0, int wave, int lane)
{
  const int m = lane & 15, kg = lane >> 4;
  const int Cpad = CB*32;
  int ot, g, gw;
  if (OT == 2){ ot = wave & 1; g = wave >> 1; gw = 4; }
  else        { ot = wave % 3; g = wave / 3; gw = (ot < 2) ? 3 : 2; }
  const int o = ot*16 + m;
  const h16* wb = Wp + (o*5)*Cpad + kg*8;
  h16x8 B[5][CB];
  #pragma unroll
  for (int k = 0; k < 5; ++k)
    #pragma unroll
    for (int cb = 0; cb < CB; ++cb)
      B[k][cb] = *(const h16x8*)(wb + k*Cpad + cb*32);
  for (int rt = g; rt < RT5; rt += gw){
    f32x4 acc0 = {0.f,0.f,0.f,0.f}, acc1 = {0.f,0.f,0.f,0.f};
    const int rbase = rt*16 + m - 2;
    #pragma unroll
    for (int k = 0; k < 5; ++k){
      const int r = clampi(rbase + k, 0, ROWS-1);
      const h16* ap = XT + r*S + kg*8;
      #pragma unroll
      for (int cb = 0; cb < CB; ++cb){
        if (((k*CB + cb) & 1) == 0) acc0 = MFMA16(*(const h16x8*)(ap + cb*32), B[k][cb], acc0);
        else                        acc1 = MFMA16(*(const h16x8*)(ap + cb*32), B[k][cb], acc1);
      }
    }
    const f32x4 acc = acc0 + acc1;
    if (o < Oreal){
      #pragma unroll
      for (int r4 = 0; r4 < 4; ++r4){
        const int row = rt*16 + kg*4 + r4;
        const bool dz = ((unsigned)(d0 - 8 + row) < 512u);
        const float v = acc[r4];
        XTo[row*So + co + o] = dz ? (h16)((EPI == 1) ? eluf(v) : v) : (h16)0.f;
      }
    }
  }
}

// chunk-merge step=4 -> out1 cols 8j..8j+8. SA = out0 stride, SB = lt1 stride.
template<int SA, int SB>
__device__ __forceinline__ void chunk4(const h16* __restrict__ out0, const h16* __restrict__ lt1,
    const h16* __restrict__ wA, const h16* __restrict__ wB, h16* __restrict__ out1,
    int d0, int wave, int lane)
{
  const int m = lane & 15, kg = lane >> 4;
  const h16x8 bA = *(const h16x8*)(wA + m*32 + kg*8);
  const h16x8 bB = *(const h16x8*)(wB + m*32 + kg*8);
  for (int tix = wave; tix < 6*RT5; tix += 8){
    const int j = tix / RT5, rt = tix - j*RT5;
    const int rb = rt*16 + m;
    const int r0 = clampi(rb + 2*kg - 2, 0, ROWS-1);
    const int r1 = clampi(rb + 2*kg - 1, 0, ROWS-1);
    h16x4 lo = *(const h16x4*)(out0 + r0*SA + 4*j);
    h16x4 hi = *(const h16x4*)(out0 + r1*SA + 4*j);
    h16x8 a = __builtin_shufflevector(lo, hi, 0,1,2,3,4,5,6,7);
    f32x4 accA = {0.f,0.f,0.f,0.f};
    accA = MFMA16(a, bA, accA);
    lo = *(const h16x4*)(lt1 + r0*SB + 4*j);
    hi = *(const h16x4*)(lt1 + r1*SB + 4*j);
    a = __builtin_shufflevector(lo, hi, 0,1,2,3,4,5,6,7);
    f32x4 accB = {0.f,0.f,0.f,0.f};
    accB = MFMA16(a, bB, accB);
    if (m < 8){
      #pragma unroll
      for (int r4 = 0; r4 < 4; ++r4){
        const int row = rt*16 + kg*4 + r4;
        const bool dz = ((unsigned)(d0 - 8 + row) < 512u);
        out1[row*S56 + 8*j + m] = dz ? (h16)(eluf(accA[r4]) + eluf(accB[r4])) : (h16)0.f;
      }
    }
  }
}

// ---------------- main fused kernel: one workgroup per batch element ----------------
__global__ __launch_bounds__(512, 4) void decoder_fused(
    const float* __restrict__ enc_true, const float* __restrict__ enc_pred,
    const float* __restrict__ lot0, const float* __restrict__ lot1,
    const float* __restrict__ lop0, const float* __restrict__ lop1,
    const h16* __restrict__ wp, const float* __restrict__ w_lin,
    const float* __restrict__ b_lin, float* __restrict__ out)
{
  // LDS arena: 81,856 B -> 2 WGs/CU (163,712 <= 163,840).
  __shared__ __align__(16) char smem[81856];
  float* PROJ = (float*)smem;                 // [35][144] fp32   20160 B
  h16* IN = (h16*)(smem + 20160);             // input staging    11520 B (80xS72)
  h16* A  = (h16*)(smem + 31680);             // s / lt1 / projF   6400 B (80xS40)
  h16* Bb = (h16*)(smem + 38080);             // out0 / lt0        8960 B (80xS56)
  h16* CC = (h16*)(smem + 47040);             // cc1 / cc0        16640 B (80xS104)
  h16* D  = (h16*)(smem + 63680);             // out1              8960 B (80xS56)
  h16* O2a = (h16*)(smem + 72640);            // OUT2T buf 0       4608 B (32xSO2)
  h16* O2b = (h16*)(smem + 77248);            // OUT2T buf 1       4608 B

  const int b = blockIdx.x;
  const int tid = threadIdx.x;
  const int wave = tid >> 6, lane = tid & 63;
  const int m16 = lane & 15, kg4 = lane >> 4;

  const float* p_true = enc_true + (size_t)b*32*512;
  const float* p_pred = enc_pred + (size_t)b*24*512;
  const float* p_lot1 = lot1 + (size_t)b*32*512;
  const float* p_lop1 = lop1 + (size_t)b*24*512;
  const float* p_lot0 = lot0 + (size_t)b*64*512;
  const float* p_lop0 = lop0 + (size_t)b*48*512;

  for (int i = tid; i < 35*144; i += 512) PROJ[i] = 0.f;
  // prologue: enc inputs for tile 0 -> IN[0:32]=true, IN[32:56]=pred, [56:64)=0 (C-guard)
  loadT(p_true, 32, 2, IN, S72, 0, 0, wave, lane);
  loadT(p_pred, 24, 2, IN, S72, 32, 0, wave, lane);
  __syncthreads();

  for (int t = 0; t < 8; ++t){
    const int d0 = t*64;

    // span1: s = conv([true;pred], WAUG) -> A  (plain store, identity adds pred)
    convGemm<2,2,2>(IN, S72, wp+OFF_WAUG, A, S40, 0, 32, d0, wave, lane);
    __syncthreads();

    // span2: out0 = elu(conv(s)) -> Bb ; load lot1 -> IN
    convGemm<1,2,1>(A, S40, wp+OFF_WOUT, Bb, S56, 0, 32, d0, wave, lane);
    loadT(p_lot1, 32, 2, IN, S72, 0, d0, wave, lane);
    __syncthreads();

    // span3: lt1a = elu(conv(lot1)) -> CC[0:24] ; load lop1 -> CC[24:56) ; zero [56:64)
    convGemm<1,2,1>(IN, S72, wp+OFF_WTE1, CC, S104, 0, 24, d0, wave, lane);
    loadT(p_lop1, 24, 2, CC, S104, 24, d0, wave, lane);
    zeroCols(CC, S104, 56, 8, tid);
    __syncthreads();

    // span4: lt1 = elu(conv(cc1)) -> A ; load lot0 -> IN
    convGemm<2,2,1>(CC, S104, wp+OFF_WCM1, A, S40, 0, 32, d0, wave, lane);
    loadT(p_lot0, 64, 4, IN, S72, 0, d0, wave, lane);
    __syncthreads();

    // span5 (merged): out1 = chunk4(out0@S56, lt1@S40) -> D ; lt0a -> CC[0:48)
    //                 ; load lop0 -> CC[48:96)
    chunk4<S56,S40>(Bb, A, wp+OFF_WM0, wp+OFF_WM20, D, d0, wave, lane);
    convGemm<2,3,1>(IN, S72, wp+OFF_WTE0, CC, S104, 0, 48, d0, wave, lane);
    loadT(p_lop0, 48, 3, CC, S104, 48, d0, wave, lane);
    __syncthreads();

    // span6: lt0 = elu(conv(cc0)) -> Bb ; prefetch next tile's enc inputs -> IN
    convGemm<3,3,1>(CC, S104, wp+OFF_WCM0, Bb, S56, 0, 48, d0, wave, lane);
    if (t < 7){
      loadT(p_true, 32, 2, IN, S72, 0, d0 + 64, wave, lane);
      loadT(p_pred, 24, 2, IN, S72, 32, d0 + 64, wave, lane);
    }
    __syncthreads();

    // S8: chunk8(D,Bb) -> O2[j&1] ; projAcc -> PROJ.  Frags hoisted out of j-loop.
    const int o8 = (wave >> 2)*16 + m16;
    const h16* wA8 = wp + OFF_WM1  + o8*64 + kg4*8;
    const h16* wB8 = wp + OFF_WM21 + o8*64 + kg4*8;
    const h16x8 bA0 = *(const h16x8*)(wA8);
    const h16x8 bA1 = *(const h16x8*)(wA8 + 32);
    const h16x8 bB0 = *(const h16x8*)(wB8);
    const h16x8 bB1 = *(const h16x8*)(wB8 + 32);
    h16x8 apf0{}, apf1{};
    if (wave < 6){
      const h16* ap = wp + OFF_WP + ((wave >> 1)*16 + m16)*512 + d0 + kg4*8;
      apf0 = *(const h16x8*)(ap);
      apf1 = *(const h16x8*)(ap + 32);
    }
    const int rb8 = (wave & 3)*16 + m16 + 8;       // dloc row (8..71)
    const int rA0 = rb8 + kg4 - 2;                 // in [6,72] — no clamp needed
    const int rA1 = rb8 + kg4 + 2;                 // in [10,76]
    for (int j = 0; j < 6; ++j){
      h16* o2 = (j & 1) ? O2b : O2a;
      {
        h16x8 a0 = *(const h16x8*)(D + rA0*S56 + 8*j);
        h16x8 a1 = *(const h16x8*)(D + rA1*S56 + 8*j);
        f32x4 accA = {0.f,0.f,0.f,0.f};
        accA = MFMA16(a0, bA0, accA);
        accA = MFMA16(a1, bA1, accA);
        a0 = *(const h16x8*)(Bb + rA0*S56 + 8*j);
        a1 = *(const h16x8*)(Bb + rA1*S56 + 8*j);
        f32x4 accB = {0.f,0.f,0.f,0.f};
        accB = MFMA16(a0, bB0, accB);
        accB = MFMA16(a1, bB1, accB);
        h16x4 pk;
        #pragma unroll
        for (int r4 = 0; r4 < 4; ++r4)
          pk[r4] = (h16)(eluf(accA[r4]) + eluf(accB[r4]));
        *(h16x4*)(o2 + o8*SO2 + (wave & 3)*16 + kg4*4) = pk;
      }
      __syncthreads();
      if (wave < 6){
        f32x4 acc = {0.f,0.f,0.f,0.f};
        const h16* bp = o2 + ((wave & 1)*16 + m16)*SO2 + kg4*8;
        acc = MFMA16(apf0, *(const h16x8*)(bp), acc);
        acc = MFMA16(apf1, *(const h16x8*)(bp + 32), acc);
        const int pl = (wave & 1)*16 + m16;
        if (pl < 24){
          #pragma unroll
          for (int r4 = 0; r4 < 4; ++r4){
            const int rowm = (wave >> 1)*16 + kg4*4 + r4;
            if (rowm < 35) PROJ[rowm*144 + j*24 + pl] += acc[r4];
          }
        }
      }
    }
  }
  __syncthreads();   // PROJ complete

  // Final: circular-combine PROJ -> proj[7][144], then Linear(144,144) + bias.
  float* projF = (float*)A;
  for (int i = tid; i < 7*144; i += 512){
    const int jj = i / 144, p = i - jj*144;
    float s = 0.f;
    #pragma unroll
    for (int k = 0; k < 5; ++k){
      int pp = p + k - 2; pp = (pp + 144) % 144;
      s += PROJ[(jj*5 + k)*144 + pp];
    }
    projF[i] = s;
  }
  __syncthreads();
  for (int i = tid; i < 1008; i += 512){
    const int o = i / 7, jj = i - o*7;
    float acc = b_lin[o];
    const float* wl = w_lin + o*144;
    const float* pr = (const float*)projF + jj*144;
    for (int p = 0; p < 144; ++p) acc += pr[p] * wl[p];
    out[(size_t)b*1008 + i] = acc;
  }
}

extern "C" void kernel_launch(void* const* d_in, const int* in_sizes, int n_in,
                              void* d_out, int out_size, void* d_ws, size_t ws_size,
                              hipStream_t stream)
{
  if (ws_size < (size_t)PACKED_TOTAL * sizeof(h16)) return;
  h16* wp = (h16*)d_ws;
  pack_weights<<<9, 256, 0, stream>>>(
      (const float*)d_in[6],  // w_conv_z1
      (const float*)d_in[7],  // w_conv_output
      (const float*)d_in[9],  // w_te1
      (const float*)d_in[11], // w_cm1
      (const float*)d_in[8],  // w_te0
      (const float*)d_in[10], // w_cm0
      (const float*)d_in[12], // w_m0
      (const float*)d_in[13], // w_m20
      (const float*)d_in[14], // w_m1
      (const float*)d_in[15], // w_m21
      (const float*)d_in[16], // w_proj
      wp);
  decoder_fused<<<512, 512, 0, stream>>>(
      (const float*)d_in[0], (const float*)d_in[1],
      (const float*)d_in[2], (const float*)d_in[3],
      (const float*)d_in[4], (const float*)d_in[5],
      wp, (const float*)d_in[17], (const float*)d_in[18],
      (float*)d_out);
}